// Round 5
// baseline (424.876 us; speedup 1.0000x reference)
//
#include <hip/hip_runtime.h>

#define T_SEQ 2048
#define C_DIM 1024
#define NH    16
#define NKV   4
#define HD    64
#define WIN   512

typedef __bf16 bf16x8 __attribute__((ext_vector_type(8)));
typedef __bf16 bf16x4 __attribute__((ext_vector_type(4)));
typedef float f32x4 __attribute__((ext_vector_type(4)));
typedef float f32x16 __attribute__((ext_vector_type(16)));

#define MFMA16(a, b, c) __builtin_amdgcn_mfma_f32_16x16x32_bf16(a, b, c, 0, 0, 0)
#define MFMA32(a, b, c) __builtin_amdgcn_mfma_f32_32x32x16_bf16(a, b, c, 0, 0, 0)

// async global->LDS, 16B per lane, dest = wave-uniform base + lane*16
#define GLD16(g, s)                                                          \
  __builtin_amdgcn_global_load_lds(                                          \
      (const __attribute__((address_space(1))) void*)(g),                    \
      (__attribute__((address_space(3))) void*)(s), 16, 0, 0)

// ---------------- prep: fused f32->bf16 casts + RoPE table (R7, proven) ----------------
__global__ __launch_bounds__(256) void prep_kernel(const float* __restrict__ x,
                                                   const float* __restrict__ Wq,
                                                   const float* __restrict__ Wkv,
                                                   const float* __restrict__ Wp,
                                                   __bf16* __restrict__ xb,
                                                   __bf16* __restrict__ Wqkvb,
                                                   __bf16* __restrict__ Wpb,
                                                   float2* __restrict__ ropeT) {
  int b = blockIdx.x;
  if (b >= 4608) {
    int idx = (b - 4608) * 256 + threadIdx.x;  // < 65536
    int t = idx >> 5, i = idx & 31;
    float theta = exp2f(-(float)i * (13.287712379549449f / 32.0f));
    float s, c;
    sincosf((float)t * theta, &s, &c);
    ropeT[idx] = make_float2(c, s);
    return;
  }
  const float* src;
  __bf16* dst;
  int off;
  if (b < 2048)      { src = x;   dst = xb;                off = b; }
  else if (b < 3072) { src = Wq;  dst = Wqkvb;             off = b - 2048; }
  else if (b < 3584) { src = Wkv; dst = Wqkvb + (1 << 20); off = b - 3072; }
  else               { src = Wp;  dst = Wpb;               off = b - 3584; }
  int i = off * 1024 + threadIdx.x * 4;
  float4 v = *(const float4*)(src + i);
  bf16x4 o;
  o[0] = (__bf16)v.x; o[1] = (__bf16)v.y; o[2] = (__bf16)v.z; o[3] = (__bf16)v.w;
  *(bf16x4*)(dst + i) = o;
}

// ---------------- GEMM core: 64x64 tile, BK=64, K-SPLIT across waves, 32x32x16 MFMA ----
// R13: LDS-read demand was ~3x MFMA demand (10 b128 reads per 8 small MFMA).
// New: each wave computes the FULL 64x64 tile for its OWN K=16 slab (sc = w*2+hi):
// 4 MFMA (32x32x16, 2x FLOP/operand-byte) and only 4 ds_read_b128 per iter
// -> 1 read/MFMA, 2.5x better FLOP per LDS byte. K-partials accumulate in 64
// AGPRs; 3-barrier LDS tree-reduction leaves wave0 owning rows 0-31 (acc[0]) and
// wave1 rows 32-63 (acc[1]). Staging identical to R1 (gld_lds + source XOR).
// C/D layout (m101-verified): col = lane&31, row = (reg&3)+8*(reg>>2)+4*(lane>>5).
__device__ __forceinline__ void gemm_core64(const __bf16* __restrict__ A,
                                            const __bf16* __restrict__ B,
                                            int K,
                                            __bf16* smem,   // 32 KB
                                            f32x16 (&acc)[2][2]) {
  const int tid = threadIdx.x;
  const int w = tid >> 6, l = tid & 63;
  const int hi = l >> 5, c = l & 31;
  // staging (unchanged): wave w fills rows [w*16, w*16+16) of A and B tiles
  const int srow = w * 16 + (l >> 3);
  const size_t soff = (size_t)srow * K + (size_t)(((l & 7) ^ (l >> 3)) * 8);
  const __bf16* gA = A + soff;
  const __bf16* gB = B + soff;
  __bf16* AsB = smem;
  __bf16* BsB = smem + 8192;
  __bf16* const lA = AsB + w * 1024;
  __bf16* const lB = BsB + w * 1024;
  const size_t rstep = (size_t)8 * K;
  // fragment offsets: wave w's k-slab chunk sc; row/col = c + {0,32}
  const int sc = w * 2 + hi;
  int off[2];
#pragma unroll
  for (int mi = 0; mi < 2; ++mi) {
    int row = c + mi * 32;
    off[mi] = row * 64 + ((sc ^ (row & 7)) * 8);
  }
  const int nIter = K >> 6;
  GLD16(gA, lA); GLD16(gA + rstep, lA + 512);
  GLD16(gB, lB); GLD16(gB + rstep, lB + 512);
  __syncthreads();
  int cur = 0;
  for (int it = 0; it < nIter; ++it) {
    if (it + 1 < nIter) {  // async-stage next K-slab into the other buffer
      const __bf16* ga = gA + ((it + 1) << 6);
      const __bf16* gb = gB + ((it + 1) << 6);
      __bf16* la = lA + ((cur ^ 1) << 12);
      __bf16* lb = lB + ((cur ^ 1) << 12);
      GLD16(ga, la); GLD16(ga + rstep, la + 512);
      GLD16(gb, lb); GLD16(gb + rstep, lb + 512);
    }
    const __bf16* Asc = AsB + (cur << 12);
    const __bf16* Bsc = BsB + (cur << 12);
    bf16x8 a0 = *(const bf16x8*)(Asc + off[0]);
    bf16x8 a1 = *(const bf16x8*)(Asc + off[1]);
    bf16x8 b0 = *(const bf16x8*)(Bsc + off[0]);
    bf16x8 b1 = *(const bf16x8*)(Bsc + off[1]);
    acc[0][0] = MFMA32(a0, b0, acc[0][0]);
    acc[0][1] = MFMA32(a0, b1, acc[0][1]);
    acc[1][0] = MFMA32(a1, b0, acc[1][0]);
    acc[1][1] = MFMA32(a1, b1, acc[1][1]);
    if (it + 1 < nIter) {
      __syncthreads();  // drains vmcnt(0): next slab resident; old buffer free
      cur ^= 1;
    }
  }
  // ---- K-partition tree reduction over LDS (staging buffers are dead) ----
  __syncthreads();                       // last tile's reads complete everywhere
  float* R0 = (float*)smem;              // 16 KB = [64 rows][64 cols] f32
  float* R1 = (float*)smem + 4096;
  if (w >= 2) {                          // round 1: waves 2,3 publish full partials
    float* R = (w == 2) ? R0 : R1;
#pragma unroll
    for (int mi = 0; mi < 2; ++mi)
#pragma unroll
      for (int nj = 0; nj < 2; ++nj)
#pragma unroll
        for (int g = 0; g < 16; ++g) {
          int row = (g & 3) + 8 * (g >> 2) + 4 * hi + mi * 32;
          R[row * 64 + nj * 32 + c] = acc[mi][nj][g];
        }
  }
  __syncthreads();
  if (w < 2) {                           // waves 0,1 absorb
    const float* R = (w == 0) ? R0 : R1;
#pragma unroll
    for (int mi = 0; mi < 2; ++mi)
#pragma unroll
      for (int nj = 0; nj < 2; ++nj)
#pragma unroll
        for (int g = 0; g < 16; ++g) {
          int row = (g & 3) + 8 * (g >> 2) + 4 * hi + mi * 32;
          acc[mi][nj][g] += R[row * 64 + nj * 32 + c];
        }
  }
  __syncthreads();
  if (w < 2) {                           // round 2: swap m-halves (w1's mi0 -> R0, w0's mi1 -> R1)
    float* Rw = (w == 0) ? R1 : R0;
    const int mi = 1 - w;                // half given away
#pragma unroll
    for (int nj = 0; nj < 2; ++nj)
#pragma unroll
      for (int g = 0; g < 16; ++g) {
        int rl = (g & 3) + 8 * (g >> 2) + 4 * hi;   // local row within half
        Rw[rl * 64 + nj * 32 + c] = acc[mi][nj][g];
      }
  }
  __syncthreads();
  if (w < 2) {
    const float* Rr = (w == 0) ? R0 : R1;
    const int mi = w;                    // half kept: final rows = mi*32 + rl
#pragma unroll
    for (int nj = 0; nj < 2; ++nj)
#pragma unroll
      for (int g = 0; g < 16; ++g) {
        int rl = (g & 3) + 8 * (g >> 2) + 4 * hi;
        acc[mi][nj][g] += Rr[rl * 64 + nj * 32 + c];
      }
  }
  __syncthreads();                       // smem free for epilogue reuse
}

// ---------------- QKV GEMM + fused norm+RoPE (Q,K) / V-transpose epilogue ----------
// grid (24, 32). Epilogue on waves 0,1 only (they own the reduced tile halves).
// 32x32 C/D layout: lane holds cols c and c+32 -> RoPE pair (d, d+32) is
// lane-local; row-norm = shfl_xor reduce over each 32-lane half (masks 1..16).
__global__ __launch_bounds__(256) void gemm_qkv_kernel(const __bf16* __restrict__ xb,
                                                       const __bf16* __restrict__ Wqkvb,
                                                       const float2* __restrict__ ropeT,
                                                       __bf16* __restrict__ Qb,
                                                       __bf16* __restrict__ Kb,
                                                       __bf16* __restrict__ Vt) {
  __shared__ __align__(16) __bf16 smem[16384];  // 32 KB
  f32x16 acc[2][2] = {};
  const int m0 = blockIdx.y * 64, n0 = blockIdx.x * 64;
  gemm_core64(xb + (size_t)m0 * C_DIM, Wqkvb + (size_t)n0 * C_DIM, C_DIM, smem, acc);
  const int tid = threadIdx.x;
  const int w = tid >> 6, l = tid & 63, hi = l >> 5, c = l & 31;
  if (n0 < 1280) {  // Q or K: L2-norm + RoPE
    const bool isQ = n0 < 1024;
    const int head = isQ ? (n0 >> 6) : ((n0 - 1024) >> 6);
    __bf16* dstBase = (isQ ? Qb : Kb) + (size_t)head * T_SEQ * HD;
    const float osc = isQ ? 0.125f : 1.0f;  // fold 1/sqrt(d) into Q (2^-3 exact)
    if (w < 2) {
#pragma unroll
      for (int g = 0; g < 16; ++g) {
        float a0 = acc[w][0][g], a1 = acc[w][1][g];
        float ss = a0 * a0 + a1 * a1;
#pragma unroll
        for (int m = 1; m < 32; m <<= 1) ss += __shfl_xor(ss, m, 64);
        const float inv = osc / (sqrtf(ss) + 1e-6f);
        const int t = m0 + (g & 3) + 8 * (g >> 2) + 4 * hi + w * 32;
        const float2 cs = ropeT[t * 32 + c];
        const float v0 = a0 * inv, v1 = a1 * inv;
        __bf16* dst = dstBase + (size_t)t * HD;
        dst[c]      = (__bf16)(v0 * cs.x - v1 * cs.y);
        dst[c + 32] = (__bf16)(v1 * cs.x + v0 * cs.y);
      }
    }
  } else {  // V: transpose to Vt[kvh][d][t] via reused LDS
    const int kvh = (n0 - 1280) >> 6;
    __bf16* Vs = smem;  // [64 d][stride 72] = 9.2 KB
    if (w < 2) {
#pragma unroll
      for (int nj = 0; nj < 2; ++nj)
#pragma unroll
        for (int g = 0; g < 16; ++g) {
          int row = (g & 3) + 8 * (g >> 2) + 4 * hi + w * 32;
          Vs[(nj * 32 + c) * 72 + row] = (__bf16)acc[w][nj][g];
        }
    }
    __syncthreads();
    const int d = tid >> 2, tc = (tid & 3) * 16;
    __bf16* dst = Vt + ((size_t)kvh * HD + d) * T_SEQ + m0 + tc;
    bf16x8 v0 = *(const bf16x8*)(Vs + d * 72 + tc);
    bf16x8 v1 = *(const bf16x8*)(Vs + d * 72 + tc + 8);
    *(bf16x8*)dst = v0;
    *(bf16x8*)(dst + 8) = v1;
  }
}

// ---------------- proj GEMM: grid (16, 32), f32 epilogue on waves 0,1 ----------------
__global__ __launch_bounds__(256) void gemm_proj_kernel(const __bf16* __restrict__ Yb,
                                                        const __bf16* __restrict__ Wpb,
                                                        float* __restrict__ C) {
  __shared__ __align__(16) __bf16 smem[16384];
  f32x16 acc[2][2] = {};
  const int m0 = blockIdx.y * 64, n0 = blockIdx.x * 64;
  gemm_core64(Yb + (size_t)m0 * C_DIM, Wpb + (size_t)n0 * C_DIM, C_DIM, smem, acc);
  const int tid = threadIdx.x;
  const int w = tid >> 6, l = tid & 63, hi = l >> 5, c = l & 31;
  if (w < 2) {
#pragma unroll
    for (int nj = 0; nj < 2; ++nj)
#pragma unroll
      for (int g = 0; g < 16; ++g) {
        const int row = (g & 3) + 8 * (g >> 2) + 4 * hi + w * 32;
        C[(size_t)(m0 + row) * C_DIM + n0 + nj * 32 + c] = acc[w][nj][g];
      }
  }
}

// ---------------- MFMA sliding-window attention, block-cooperative LDS-staged ----------
// R12 (proven, -31 us): block = 64 queries (4 waves x 16 rows); per 64-key chunk
// the block stages K+V once into LDS (gld_lds + source XOR), double-buffered;
// one __syncthreads per chunk drains vmcnt. Numerics: R7-proven epilogue math.
__global__ __launch_bounds__(256) void attn_mfma_kernel(const __bf16* __restrict__ Qb,
                                                        const __bf16* __restrict__ Kb,
                                                        const __bf16* __restrict__ Vt,
                                                        __bf16* __restrict__ Yb) {
  __shared__ __align__(16) __bf16 KVs[2][8192];   // per buf: K[64][64] | V[64][64]
  __shared__ __align__(16) __bf16 Pl[4][16][72];
  const int h = blockIdx.y, kvh = h >> 2;
  const int t0 = blockIdx.x * 64;
  const int tid = threadIdx.x;
  const int w = tid >> 6, l = tid & 63;
  const int quad = l >> 4, r16 = l & 15;
  const int rr = l >> 3;          // 0..7: staging row within 8-row group
  const int cc = (l & 7) ^ rr;    // swizzled source chunk
  const __bf16* qptr = Qb + ((size_t)h * T_SEQ + t0 + w * 16 + r16) * HD + quad * 8;
  bf16x8 aq0 = *(const bf16x8*)(qptr);
  bf16x8 aq1 = *(const bf16x8*)(qptr + 32);
  const int keyStart = max(0, t0 - (WIN - 1)) & ~63;
  const int nch = ((t0 + 64) - keyStart) >> 6;         // <= 9, block-uniform
  const __bf16* kbase = Kb + (size_t)kvh * T_SEQ * HD;
  const __bf16* vbase = Vt + (size_t)kvh * HD * T_SEQ;
  const int tq = t0 + w * 16 + quad * 4;  // + r
  f32x4 oacc[4] = {};
  float lsum[4] = {0.f, 0.f, 0.f, 0.f};

  {  // prologue: stage chunk 0 into buf 0
    __bf16* kd = &KVs[0][w * 1024];
    __bf16* vd = &KVs[0][4096 + w * 1024];
    const __bf16* kg = kbase + (size_t)(keyStart + w * 16 + rr) * HD + cc * 8;
    const __bf16* vg = vbase + (size_t)(w * 16 + rr) * T_SEQ + keyStart + cc * 8;
    GLD16(kg, kd); GLD16(kg + 8 * HD, kd + 512);
    GLD16(vg, vd); GLD16(vg + 8 * T_SEQ, vd + 512);
  }
  __syncthreads();
  int buf = 0;
  for (int it = 0; it < nch; ++it) {
    const int key0 = keyStart + (it << 6);
    if (it + 1 < nch) {  // async-stage next chunk into the other buffer
      const int kn = key0 + 64;
      __bf16* kd = &KVs[buf ^ 1][w * 1024];
      __bf16* vd = &KVs[buf ^ 1][4096 + w * 1024];
      const __bf16* kg = kbase + (size_t)(kn + w * 16 + rr) * HD + cc * 8;
      const __bf16* vg = vbase + (size_t)(w * 16 + rr) * T_SEQ + kn + cc * 8;
      GLD16(kg, kd); GLD16(kg + 8 * HD, kd + 512);
      GLD16(vg, vd); GLD16(vg + 8 * T_SEQ, vd + 512);
    }
    const __bf16* Ksc = &KVs[buf][0];
    const __bf16* Vsc = &KVs[buf][4096];
    f32x4 s[4] = {};
#pragma unroll
    for (int nt = 0; nt < 4; ++nt) {
      const int row = nt * 16 + r16;
      bf16x8 bk0 = *(const bf16x8*)(Ksc + row * 64 + ((quad ^ (row & 7)) * 8));
      bf16x8 bk1 = *(const bf16x8*)(Ksc + row * 64 + (((4 + quad) ^ (row & 7)) * 8));
      s[nt] = MFMA16(aq0, bk0, s[nt]);
      s[nt] = MFMA16(aq1, bk1, s[nt]);
    }
#pragma unroll
    for (int nt = 0; nt < 4; ++nt) {
      const int key = key0 + nt * 16 + r16;
#pragma unroll
      for (int r = 0; r < 4; ++r) {
        bool valid = (key <= tq + r) && (key > tq + r - WIN);
        float p = valid ? __expf(s[nt][r]) : 0.0f;
        lsum[r] += p;
        Pl[w][quad * 4 + r][nt * 16 + r16] = (__bf16)p;
      }
    }
    bf16x8 ap0 = *(const bf16x8*)(&Pl[w][r16][quad * 8]);
    bf16x8 ap1 = *(const bf16x8*)(&Pl[w][r16][32 + quad * 8]);
#pragma unroll
    for (int nt = 0; nt < 4; ++nt) {
      const int d = nt * 16 + r16;
      bf16x8 bv0 = *(const bf16x8*)(Vsc + d * 64 + ((quad ^ (d & 7)) * 8));
      bf16x8 bv1 = *(const bf16x8*)(Vsc + d * 64 + (((4 + quad) ^ (d & 7)) * 8));
      oacc[nt] = MFMA16(ap0, bv0, oacc[nt]);
      oacc[nt] = MFMA16(ap1, bv1, oacc[nt]);
    }
    __syncthreads();  // drains vmcnt: next chunk resident; old buffer free
    buf ^= 1;
  }
#pragma unroll
  for (int r = 0; r < 4; ++r) {
#pragma unroll
    for (int m = 1; m < 16; m <<= 1) lsum[r] += __shfl_xor(lsum[r], m, 64);
  }
#pragma unroll
  for (int r = 0; r < 4; ++r) {
    const float inv = 1.0f / lsum[r];
    const size_t row = (size_t)(tq + r);
#pragma unroll
    for (int nt = 0; nt < 4; ++nt)
      Yb[row * C_DIM + h * HD + nt * 16 + r16] = (__bf16)(oacc[nt][r] * inv);
  }
}

extern "C" void kernel_launch(void* const* d_in, const int* in_sizes, int n_in,
                              void* d_out, int out_size, void* d_ws, size_t ws_size,
                              hipStream_t stream) {
  const float* x     = (const float*)d_in[0];
  const float* Wq    = (const float*)d_in[1];
  const float* Wkv   = (const float*)d_in[2];
  const float* Wproj = (const float*)d_in[3];
  float* out = (float*)d_out;

  __bf16* xb    = (__bf16*)d_ws;                         // [2048][1024]
  __bf16* Wqkvb = xb + (size_t)T_SEQ * C_DIM;            // [1536][1024]
  __bf16* Wpb   = Wqkvb + (size_t)1536 * C_DIM;          // [1024][1024]
  __bf16* Qb    = Wpb + (size_t)C_DIM * C_DIM;           // [16][2048][64]
  __bf16* Kb    = Qb + (size_t)NH * T_SEQ * HD;          // [4][2048][64]
  __bf16* Vt    = Kb + (size_t)NKV * T_SEQ * HD;         // [4][64][2048]
  __bf16* Yb    = Vt + (size_t)NKV * HD * T_SEQ;         // [2048][1024]
  float2* ropeT = (float2*)(Yb + (size_t)T_SEQ * C_DIM); // [2048][32]

  prep_kernel<<<4864, 256, 0, stream>>>(x, Wq, Wkv, Wproj, xb, Wqkvb, Wpb, ropeT);
  gemm_qkv_kernel<<<dim3(24, 32), 256, 0, stream>>>(xb, Wqkvb, ropeT, Qb, Kb, Vt);
  attn_mfma_kernel<<<dim3(T_SEQ / 64, NH), 256, 0, stream>>>(Qb, Kb, Vt, Yb);
  gemm_proj_kernel<<<dim3(16, 32), 256, 0, stream>>>(Yb, Wpb, out);
}

// Round 7
// 125.596 us; speedup vs baseline: 3.3829x; 3.3829x over previous
//
#include <hip/hip_runtime.h>

#define T_SEQ 2048
#define C_DIM 1024
#define NH    16
#define NKV   4
#define HD    64
#define WIN   512

typedef __bf16 bf16x8 __attribute__((ext_vector_type(8)));
typedef __bf16 bf16x4 __attribute__((ext_vector_type(4)));
typedef float f32x4 __attribute__((ext_vector_type(4)));
typedef float f32x16 __attribute__((ext_vector_type(16)));

#define MFMA16(a, b, c) __builtin_amdgcn_mfma_f32_16x16x32_bf16(a, b, c, 0, 0, 0)
#define MFMA32(a, b, c) __builtin_amdgcn_mfma_f32_32x32x16_bf16(a, b, c, 0, 0, 0)

// async global->LDS, 16B per lane, dest = wave-uniform base + lane*16
#define GLD16(g, s)                                                          \
  __builtin_amdgcn_global_load_lds(                                          \
      (const __attribute__((address_space(1))) void*)(g),                    \
      (__attribute__((address_space(3))) void*)(s), 16, 0, 0)

// ---------------- prep: fused f32->bf16 casts + RoPE table (R7, proven) ----------------
__global__ __launch_bounds__(256) void prep_kernel(const float* __restrict__ x,
                                                   const float* __restrict__ Wq,
                                                   const float* __restrict__ Wkv,
                                                   const float* __restrict__ Wp,
                                                   __bf16* __restrict__ xb,
                                                   __bf16* __restrict__ Wqkvb,
                                                   __bf16* __restrict__ Wpb,
                                                   float2* __restrict__ ropeT) {
  int b = blockIdx.x;
  if (b >= 4608) {
    int idx = (b - 4608) * 256 + threadIdx.x;  // < 65536
    int t = idx >> 5, i = idx & 31;
    float theta = exp2f(-(float)i * (13.287712379549449f / 32.0f));
    float s, c;
    sincosf((float)t * theta, &s, &c);
    ropeT[idx] = make_float2(c, s);
    return;
  }
  const float* src;
  __bf16* dst;
  int off;
  if (b < 2048)      { src = x;   dst = xb;                off = b; }
  else if (b < 3072) { src = Wq;  dst = Wqkvb;             off = b - 2048; }
  else if (b < 3584) { src = Wkv; dst = Wqkvb + (1 << 20); off = b - 3072; }
  else               { src = Wp;  dst = Wpb;               off = b - 3584; }
  int i = off * 1024 + threadIdx.x * 4;
  float4 v = *(const float4*)(src + i);
  bf16x4 o;
  o[0] = (__bf16)v.x; o[1] = (__bf16)v.y; o[2] = (__bf16)v.z; o[3] = (__bf16)v.w;
  *(bf16x4*)(dst + i) = o;
}

// ---------------- GEMM core: 64x64 tile, BK=64, K-SPLIT across waves, 32x32x16 MFMA ----
// R14 = R13 with rule-#20 fixed: R5's 425us regression was acc[w]/acc[1-w] RUNTIME
// indexing -> whole accumulator demoted to scratch (WRITE_SIZE 528MB/dispatch).
// ALL acc indices are now compile-time constants; wave-uniform w appears only in
// branches. Structure: each wave computes the full 64x64 tile for its own K=16
// slab (sc = w*2+hi): 4 MFMA 32x32x16 + 4 ds_read_b128 per iter (1 read/MFMA).
// 3-barrier LDS tree-reduction leaves wave0 rows 0-31 in acc[0][*], wave1 rows
// 32-63 in acc[1][*]. Staging identical to R1 (gld_lds + source XOR swizzle).
// C/D layout (m101): col = lane&31, row = (reg&3)+8*(reg>>2)+4*(lane>>5).
__device__ __forceinline__ void gemm_core64(const __bf16* __restrict__ A,
                                            const __bf16* __restrict__ B,
                                            int K,
                                            __bf16* smem,   // 32 KB
                                            f32x16 (&acc)[2][2]) {
  const int tid = threadIdx.x;
  const int w = tid >> 6, l = tid & 63;
  const int hi = l >> 5, c = l & 31;
  // staging: wave w fills rows [w*16, w*16+16) of A and B tiles
  const int srow = w * 16 + (l >> 3);
  const size_t soff = (size_t)srow * K + (size_t)(((l & 7) ^ (l >> 3)) * 8);
  const __bf16* gA = A + soff;
  const __bf16* gB = B + soff;
  __bf16* AsB = smem;
  __bf16* BsB = smem + 8192;
  __bf16* const lA = AsB + w * 1024;
  __bf16* const lB = BsB + w * 1024;
  const size_t rstep = (size_t)8 * K;
  // fragment offsets: wave w's k-slab chunk sc; rows c and c+32
  const int sc = w * 2 + hi;
  const int off0 = c * 64 + ((sc ^ (c & 7)) * 8);
  const int off1 = (c + 32) * 64 + ((sc ^ (c & 7)) * 8);  // (c+32)&7 == c&7
  const int nIter = K >> 6;
  GLD16(gA, lA); GLD16(gA + rstep, lA + 512);
  GLD16(gB, lB); GLD16(gB + rstep, lB + 512);
  __syncthreads();
  int cur = 0;
  for (int it = 0; it < nIter; ++it) {
    if (it + 1 < nIter) {  // async-stage next K-slab into the other buffer
      const __bf16* ga = gA + ((it + 1) << 6);
      const __bf16* gb = gB + ((it + 1) << 6);
      __bf16* la = lA + ((cur ^ 1) << 12);
      __bf16* lb = lB + ((cur ^ 1) << 12);
      GLD16(ga, la); GLD16(ga + rstep, la + 512);
      GLD16(gb, lb); GLD16(gb + rstep, lb + 512);
    }
    const __bf16* Asc = AsB + (cur << 12);
    const __bf16* Bsc = BsB + (cur << 12);
    bf16x8 a0 = *(const bf16x8*)(Asc + off0);
    bf16x8 a1 = *(const bf16x8*)(Asc + off1);
    bf16x8 b0 = *(const bf16x8*)(Bsc + off0);
    bf16x8 b1 = *(const bf16x8*)(Bsc + off1);
    acc[0][0] = MFMA32(a0, b0, acc[0][0]);
    acc[0][1] = MFMA32(a0, b1, acc[0][1]);
    acc[1][0] = MFMA32(a1, b0, acc[1][0]);
    acc[1][1] = MFMA32(a1, b1, acc[1][1]);
    if (it + 1 < nIter) {
      __syncthreads();  // drains vmcnt(0): next slab resident; old buffer free
      cur ^= 1;
    }
  }
  // ---- K-partition tree reduction over LDS (all acc indices STATIC) ----
  __syncthreads();                       // staging buffers dead
  float* R0 = (float*)smem;              // 16 KB = [64 rows][64 cols] f32
  float* R1 = (float*)smem + 4096;
  if (w >= 2) {                          // round 1: waves 2,3 publish full partials
    float* R = (w == 2) ? R0 : R1;
#pragma unroll
    for (int mi = 0; mi < 2; ++mi)
#pragma unroll
      for (int nj = 0; nj < 2; ++nj)
#pragma unroll
        for (int g = 0; g < 16; ++g) {
          int row = (g & 3) + 8 * (g >> 2) + 4 * hi + mi * 32;
          R[row * 64 + nj * 32 + c] = acc[mi][nj][g];
        }
  }
  __syncthreads();
  if (w < 2) {                           // waves 0,1 absorb (static mi via unroll)
    const float* R = (w == 0) ? R0 : R1;
#pragma unroll
    for (int mi = 0; mi < 2; ++mi)
#pragma unroll
      for (int nj = 0; nj < 2; ++nj)
#pragma unroll
        for (int g = 0; g < 16; ++g) {
          int row = (g & 3) + 8 * (g >> 2) + 4 * hi + mi * 32;
          acc[mi][nj][g] += R[row * 64 + nj * 32 + c];
        }
  }
  __syncthreads();
  // round 2: swap m-halves. STATIC bodies per wave (rule #20).
  if (w == 0) {                          // give away m-half 1 -> R1
#pragma unroll
    for (int nj = 0; nj < 2; ++nj)
#pragma unroll
      for (int g = 0; g < 16; ++g) {
        int rl = (g & 3) + 8 * (g >> 2) + 4 * hi;
        R1[rl * 64 + nj * 32 + c] = acc[1][nj][g];
      }
  } else if (w == 1) {                   // give away m-half 0 -> R0
#pragma unroll
    for (int nj = 0; nj < 2; ++nj)
#pragma unroll
      for (int g = 0; g < 16; ++g) {
        int rl = (g & 3) + 8 * (g >> 2) + 4 * hi;
        R0[rl * 64 + nj * 32 + c] = acc[0][nj][g];
      }
  }
  __syncthreads();
  if (w == 0) {                          // keep m-half 0 (rows 0-31)
#pragma unroll
    for (int nj = 0; nj < 2; ++nj)
#pragma unroll
      for (int g = 0; g < 16; ++g) {
        int rl = (g & 3) + 8 * (g >> 2) + 4 * hi;
        acc[0][nj][g] += R0[rl * 64 + nj * 32 + c];
      }
  } else if (w == 1) {                   // keep m-half 1 (rows 32-63)
#pragma unroll
    for (int nj = 0; nj < 2; ++nj)
#pragma unroll
      for (int g = 0; g < 16; ++g) {
        int rl = (g & 3) + 8 * (g >> 2) + 4 * hi;
        acc[1][nj][g] += R1[rl * 64 + nj * 32 + c];
      }
  }
  __syncthreads();                       // smem free for epilogue reuse
}

// pull the owned half into named regs with STATIC indices (wave-uniform branch)
#define OWN_HALF(o0, o1, acc, w)                       \
  f32x16 o0, o1;                                       \
  if (w == 0) { o0 = acc[0][0]; o1 = acc[0][1]; }      \
  else        { o0 = acc[1][0]; o1 = acc[1][1]; }

// ---------------- QKV GEMM + fused norm+RoPE (Q,K) / V-transpose epilogue ----------
// grid (24, 32). Epilogue on waves 0,1 (owners of the reduced halves). 32x32 C/D:
// lane holds cols c, c+32 -> RoPE pair (d, d+32) lane-local; norm = shfl over
// 32-lane half (masks 1..16; lanes 32-63 mirror with their own data).
__global__ __launch_bounds__(256) void gemm_qkv_kernel(const __bf16* __restrict__ xb,
                                                       const __bf16* __restrict__ Wqkvb,
                                                       const float2* __restrict__ ropeT,
                                                       __bf16* __restrict__ Qb,
                                                       __bf16* __restrict__ Kb,
                                                       __bf16* __restrict__ Vt) {
  __shared__ __align__(16) __bf16 smem[16384];  // 32 KB
  f32x16 acc[2][2] = {};
  const int m0 = blockIdx.y * 64, n0 = blockIdx.x * 64;
  gemm_core64(xb + (size_t)m0 * C_DIM, Wqkvb + (size_t)n0 * C_DIM, C_DIM, smem, acc);
  const int tid = threadIdx.x;
  const int w = tid >> 6, l = tid & 63, hi = l >> 5, c = l & 31;
  if (n0 < 1280) {  // Q or K: L2-norm + RoPE
    const bool isQ = n0 < 1024;
    const int head = isQ ? (n0 >> 6) : ((n0 - 1024) >> 6);
    __bf16* dstBase = (isQ ? Qb : Kb) + (size_t)head * T_SEQ * HD;
    const float osc = isQ ? 0.125f : 1.0f;  // fold 1/sqrt(d) into Q (2^-3 exact)
    if (w < 2) {
      OWN_HALF(o0, o1, acc, w);
#pragma unroll
      for (int g = 0; g < 16; ++g) {
        float a0 = o0[g], a1 = o1[g];
        float ss = a0 * a0 + a1 * a1;
#pragma unroll
        for (int m = 1; m < 32; m <<= 1) ss += __shfl_xor(ss, m, 64);
        const float inv = osc / (sqrtf(ss) + 1e-6f);
        const int t = m0 + (g & 3) + 8 * (g >> 2) + 4 * hi + w * 32;
        const float2 cs = ropeT[t * 32 + c];
        const float v0 = a0 * inv, v1 = a1 * inv;
        __bf16* dst = dstBase + (size_t)t * HD;
        dst[c]      = (__bf16)(v0 * cs.x - v1 * cs.y);
        dst[c + 32] = (__bf16)(v1 * cs.x + v0 * cs.y);
      }
    }
  } else {  // V: transpose to Vt[kvh][d][t] via reused LDS
    const int kvh = (n0 - 1280) >> 6;
    __bf16* Vs = smem;  // [64 d][stride 72] = 9.2 KB
    if (w < 2) {
      OWN_HALF(o0, o1, acc, w);
#pragma unroll
      for (int g = 0; g < 16; ++g) {
        int row = (g & 3) + 8 * (g >> 2) + 4 * hi + w * 32;
        Vs[c * 72 + row]        = (__bf16)o0[g];
        Vs[(c + 32) * 72 + row] = (__bf16)o1[g];
      }
    }
    __syncthreads();
    const int d = tid >> 2, tc = (tid & 3) * 16;
    __bf16* dst = Vt + ((size_t)kvh * HD + d) * T_SEQ + m0 + tc;
    bf16x8 v0 = *(const bf16x8*)(Vs + d * 72 + tc);
    bf16x8 v1 = *(const bf16x8*)(Vs + d * 72 + tc + 8);
    *(bf16x8*)dst = v0;
    *(bf16x8*)(dst + 8) = v1;
  }
}

// ---------------- proj GEMM: grid (16, 32), f32 epilogue on waves 0,1 ----------------
__global__ __launch_bounds__(256) void gemm_proj_kernel(const __bf16* __restrict__ Yb,
                                                        const __bf16* __restrict__ Wpb,
                                                        float* __restrict__ C) {
  __shared__ __align__(16) __bf16 smem[16384];
  f32x16 acc[2][2] = {};
  const int m0 = blockIdx.y * 64, n0 = blockIdx.x * 64;
  gemm_core64(Yb + (size_t)m0 * C_DIM, Wpb + (size_t)n0 * C_DIM, C_DIM, smem, acc);
  const int tid = threadIdx.x;
  const int w = tid >> 6, l = tid & 63, hi = l >> 5, c = l & 31;
  if (w < 2) {
    OWN_HALF(o0, o1, acc, w);
#pragma unroll
    for (int g = 0; g < 16; ++g) {
      const int row = (g & 3) + 8 * (g >> 2) + 4 * hi + w * 32;
      C[(size_t)(m0 + row) * C_DIM + n0 + c]      = o0[g];
      C[(size_t)(m0 + row) * C_DIM + n0 + 32 + c] = o1[g];
    }
  }
}

// ---------------- MFMA sliding-window attention, block-cooperative LDS-staged ----------
// R12 (proven, -31 us): block = 64 queries (4 waves x 16 rows); per 64-key chunk
// the block stages K+V once into LDS (gld_lds + source XOR), double-buffered;
// one __syncthreads per chunk drains vmcnt. Numerics: R7-proven epilogue math.
__global__ __launch_bounds__(256) void attn_mfma_kernel(const __bf16* __restrict__ Qb,
                                                        const __bf16* __restrict__ Kb,
                                                        const __bf16* __restrict__ Vt,
                                                        __bf16* __restrict__ Yb) {
  __shared__ __align__(16) __bf16 KVs[2][8192];   // per buf: K[64][64] | V[64][64]
  __shared__ __align__(16) __bf16 Pl[4][16][72];
  const int h = blockIdx.y, kvh = h >> 2;
  const int t0 = blockIdx.x * 64;
  const int tid = threadIdx.x;
  const int w = tid >> 6, l = tid & 63;
  const int quad = l >> 4, r16 = l & 15;
  const int rr = l >> 3;          // 0..7: staging row within 8-row group
  const int cc = (l & 7) ^ rr;    // swizzled source chunk
  const __bf16* qptr = Qb + ((size_t)h * T_SEQ + t0 + w * 16 + r16) * HD + quad * 8;
  bf16x8 aq0 = *(const bf16x8*)(qptr);
  bf16x8 aq1 = *(const bf16x8*)(qptr + 32);
  const int keyStart = max(0, t0 - (WIN - 1)) & ~63;
  const int nch = ((t0 + 64) - keyStart) >> 6;         // <= 9, block-uniform
  const __bf16* kbase = Kb + (size_t)kvh * T_SEQ * HD;
  const __bf16* vbase = Vt + (size_t)kvh * HD * T_SEQ;
  const int tq = t0 + w * 16 + quad * 4;  // + r
  f32x4 oacc[4] = {};
  float lsum[4] = {0.f, 0.f, 0.f, 0.f};

  {  // prologue: stage chunk 0 into buf 0
    __bf16* kd = &KVs[0][w * 1024];
    __bf16* vd = &KVs[0][4096 + w * 1024];
    const __bf16* kg = kbase + (size_t)(keyStart + w * 16 + rr) * HD + cc * 8;
    const __bf16* vg = vbase + (size_t)(w * 16 + rr) * T_SEQ + keyStart + cc * 8;
    GLD16(kg, kd); GLD16(kg + 8 * HD, kd + 512);
    GLD16(vg, vd); GLD16(vg + 8 * T_SEQ, vd + 512);
  }
  __syncthreads();
  int buf = 0;
  for (int it = 0; it < nch; ++it) {
    const int key0 = keyStart + (it << 6);
    if (it + 1 < nch) {  // async-stage next chunk into the other buffer
      const int kn = key0 + 64;
      __bf16* kd = &KVs[buf ^ 1][w * 1024];
      __bf16* vd = &KVs[buf ^ 1][4096 + w * 1024];
      const __bf16* kg = kbase + (size_t)(kn + w * 16 + rr) * HD + cc * 8;
      const __bf16* vg = vbase + (size_t)(w * 16 + rr) * T_SEQ + kn + cc * 8;
      GLD16(kg, kd); GLD16(kg + 8 * HD, kd + 512);
      GLD16(vg, vd); GLD16(vg + 8 * T_SEQ, vd + 512);
    }
    const __bf16* Ksc = &KVs[buf][0];
    const __bf16* Vsc = &KVs[buf][4096];
    f32x4 s[4] = {};
#pragma unroll
    for (int nt = 0; nt < 4; ++nt) {
      const int row = nt * 16 + r16;
      bf16x8 bk0 = *(const bf16x8*)(Ksc + row * 64 + ((quad ^ (row & 7)) * 8));
      bf16x8 bk1 = *(const bf16x8*)(Ksc + row * 64 + (((4 + quad) ^ (row & 7)) * 8));
      s[nt] = MFMA16(aq0, bk0, s[nt]);
      s[nt] = MFMA16(aq1, bk1, s[nt]);
    }
#pragma unroll
    for (int nt = 0; nt < 4; ++nt) {
      const int key = key0 + nt * 16 + r16;
#pragma unroll
      for (int r = 0; r < 4; ++r) {
        bool valid = (key <= tq + r) && (key > tq + r - WIN);
        float p = valid ? __expf(s[nt][r]) : 0.0f;
        lsum[r] += p;
        Pl[w][quad * 4 + r][nt * 16 + r16] = (__bf16)p;
      }
    }
    bf16x8 ap0 = *(const bf16x8*)(&Pl[w][r16][quad * 8]);
    bf16x8 ap1 = *(const bf16x8*)(&Pl[w][r16][32 + quad * 8]);
#pragma unroll
    for (int nt = 0; nt < 4; ++nt) {
      const int d = nt * 16 + r16;
      bf16x8 bv0 = *(const bf16x8*)(Vsc + d * 64 + ((quad ^ (d & 7)) * 8));
      bf16x8 bv1 = *(const bf16x8*)(Vsc + d * 64 + (((4 + quad) ^ (d & 7)) * 8));
      oacc[nt] = MFMA16(ap0, bv0, oacc[nt]);
      oacc[nt] = MFMA16(ap1, bv1, oacc[nt]);
    }
    __syncthreads();  // drains vmcnt: next chunk resident; old buffer free
    buf ^= 1;
  }
#pragma unroll
  for (int r = 0; r < 4; ++r) {
#pragma unroll
    for (int m = 1; m < 16; m <<= 1) lsum[r] += __shfl_xor(lsum[r], m, 64);
  }
#pragma unroll
  for (int r = 0; r < 4; ++r) {
    const float inv = 1.0f / lsum[r];
    const size_t row = (size_t)(tq + r);
#pragma unroll
    for (int nt = 0; nt < 4; ++nt)
      Yb[row * C_DIM + h * HD + nt * 16 + r16] = (__bf16)(oacc[nt][r] * inv);
  }
}

extern "C" void kernel_launch(void* const* d_in, const int* in_sizes, int n_in,
                              void* d_out, int out_size, void* d_ws, size_t ws_size,
                              hipStream_t stream) {
  const float* x     = (const float*)d_in[0];
  const float* Wq    = (const float*)d_in[1];
  const float* Wkv   = (const float*)d_in[2];
  const float* Wproj = (const float*)d_in[3];
  float* out = (float*)d_out;

  __bf16* xb    = (__bf16*)d_ws;                         // [2048][1024]
  __bf16* Wqkvb = xb + (size_t)T_SEQ * C_DIM;            // [1536][1024]
  __bf16* Wpb   = Wqkvb + (size_t)1536 * C_DIM;          // [1024][1024]
  __bf16* Qb    = Wpb + (size_t)C_DIM * C_DIM;           // [16][2048][64]
  __bf16* Kb    = Qb + (size_t)NH * T_SEQ * HD;          // [4][2048][64]
  __bf16* Vt    = Kb + (size_t)NKV * T_SEQ * HD;         // [4][64][2048]
  __bf16* Yb    = Vt + (size_t)NKV * HD * T_SEQ;         // [2048][1024]
  float2* ropeT = (float2*)(Yb + (size_t)T_SEQ * C_DIM); // [2048][32]

  prep_kernel<<<4864, 256, 0, stream>>>(x, Wq, Wkv, Wproj, xb, Wqkvb, Wpb, ropeT);
  gemm_qkv_kernel<<<dim3(24, 32), 256, 0, stream>>>(xb, Wqkvb, ropeT, Qb, Kb, Vt);
  attn_mfma_kernel<<<dim3(T_SEQ / 64, NH), 256, 0, stream>>>(Qb, Kb, Vt, Yb);
  gemm_proj_kernel<<<dim3(16, 32), 256, 0, stream>>>(Yb, Wpb, out);
}